// Round 9
// baseline (110.684 us; speedup 1.0000x reference)
//
#include <hip/hip_runtime.h>
#include <hip/hip_bf16.h>

// ---------------- constants ----------------
#define B_SZ   256
#define L_SZ   1024
#define C_SZ   64
#define HID    256
#define KQ     24576
#define WIN    125          // receptive field of last position
#define WSTART (L_SZ - WIN) // 899

// output offsets (floats)
#define OFF_LOGITS_S   0LL
#define OFF_LABELS_S   6356992LL
#define OFF_LOGITS_T   6357248LL
#define OFF_LABELS_T   12714240LL
#define OFF_LOGITS_TS  12714496LL
#define OFF_LABELS_TS  12780032LL
#define OFF_PRED_DOM   12780288LL
#define OFF_LABELS_DOM 12780800LL
#define OFF_YS         12781312LL

#define INV_T (1.0f / 0.07f)

typedef __attribute__((ext_vector_type(8))) short  bf16x8;
typedef __attribute__((ext_vector_type(4))) float  floatx4;
typedef __attribute__((ext_vector_type(16))) float floatx16;
typedef __attribute__((ext_vector_type(4))) unsigned short ushortx4;

__device__ __forceinline__ unsigned short f2bf_rne(float x) {
    unsigned u = __float_as_uint(x);
    unsigned r = u + 0x7fffu + ((u >> 16) & 1u);
    return (unsigned short)(r >> 16);
}
__device__ __forceinline__ float bf2f(unsigned short h) {
    return __uint_as_float(((unsigned)h) << 16);
}

// stride-robust LDS swizzle: 2-way (free) for stride-1, conflict-free for stride-2
__device__ __forceinline__ int swz2(int r) { return ((r >> 1) & 7) << 4; }

// ---------------- weight A-fragment prep (16x16x32 layout) ----------------
// layout: frag[(st*3+tap)*2+hilo][mt][kb]: 512 halfs = lane*8 + j
// element: W[co = mt*16 + (lane&15)][ci = kb*32 + (lane>>4)*8 + j] of stage st, tap k.
__global__ void prep_frag_kernel(const float* __restrict__ c1w,
                                 const float* __restrict__ c2w,
                                 unsigned short* __restrict__ wf) {
    int bid = blockIdx.x;            // (st*3+tap)*8 + mt*2 + kb : 240 blocks
    int kb = bid & 1, mt = (bid >> 1) & 3;
    int sttap = bid >> 3;            // 0..29
    int tap = sttap % 3, st = sttap / 3;
    int l = st >> 1, cv = st & 1;
    int tid = threadIdx.x;           // 512
    int j = tid & 7, lane = tid >> 3;
    int co = mt * 16 + (lane & 15);
    int ci = kb * 32 + (lane >> 4) * 8 + j;
    const float* src = cv ? c2w : c1w;
    float w = src[((l * 64 + co) * 64 + ci) * 3 + tap];
    unsigned short hi = f2bf_rne(w);
    unsigned short lo = f2bf_rne(w - bf2f(hi));
    size_t b0 = ((((size_t)((st * 3 + tap) * 2 + 0)) * 4 + mt) * 2 + kb) * 512 + lane * 8 + j;
    size_t b1 = ((((size_t)((st * 3 + tap) * 2 + 1)) * 4 + mt) * 2 + kb) * 512 + lane * 8 + j;
    wf[b0] = hi;
    wf[b1] = lo;
}

// ---------------- TCN encode via MFMA (R6 structure + A prefetch) ----------------
#define R0H 0
#define R0L 16384
#define R1H 32768
#define R1L 40960
#define HHB 49152
#define HLB 65536
#define SCRATCH_B 57344

__device__ __forceinline__ void loadA(bf16x8 A[3][2][2], const bf16x8* __restrict__ wf8,
                                      int st, int mt, int lane) {
#pragma unroll
    for (int tap = 0; tap < 3; ++tap)
#pragma unroll
        for (int h = 0; h < 2; ++h)
#pragma unroll
            for (int kb = 0; kb < 2; ++kb)
                A[tap][h][kb] = wf8[((((st * 3 + tap) * 2 + h) * 4 + mt) * 2 + kb) * 64 + lane];
}

__device__ __forceinline__ void copyA(bf16x8 D[3][2][2], const bf16x8 S[3][2][2]) {
#pragma unroll
    for (int tap = 0; tap < 3; ++tap)
#pragma unroll
        for (int h = 0; h < 2; ++h)
#pragma unroll
            for (int kb = 0; kb < 2; ++kb)
                D[tap][h][kb] = S[tap][h][kb];
}

template<bool RES, bool FINAL>
__device__ __forceinline__ void conv_pass(
    char* lds, const bf16x8 A[3][2][2],
    int inH, int inL, int rows_valid, int stride,
    int outH, int outL, int n_out, int tiles,
    int resH, int resL, int res_valid,
    const float* __restrict__ bias,
    int mt, int th, int lg, int li)
{
    int co0 = mt * 16 + lg * 4;
    float4 b4 = *(const float4*)(bias + co0);
    float ba[4] = {b4.x, b4.y, b4.z, b4.w};

    for (int tt = th; tt < tiles; tt += 2) {
        int i = tt * 16 + li;
        floatx4 acc = {0.f, 0.f, 0.f, 0.f};
#pragma unroll
        for (int tap = 0; tap < 3; ++tap) {
            int jr = i * stride + tap;
            jr = (jr < rows_valid - 1) ? jr : (rows_valid - 1);
            int sw = swz2(jr);
            const char* pH = lds + inH + jr * 128;
            const char* pL = lds + inL + jr * 128;
#pragma unroll
            for (int kb = 0; kb < 2; ++kb) {
                int cb = (kb * 64 + lg * 16) ^ sw;
                bf16x8 bH = *(const bf16x8*)(pH + cb);
                bf16x8 bL = *(const bf16x8*)(pL + cb);
                acc = __builtin_amdgcn_mfma_f32_16x16x32_bf16(A[tap][0][kb], bH, acc, 0, 0, 0);
                acc = __builtin_amdgcn_mfma_f32_16x16x32_bf16(A[tap][0][kb], bL, acc, 0, 0, 0);
                acc = __builtin_amdgcn_mfma_f32_16x16x32_bf16(A[tap][1][kb], bH, acc, 0, 0, 0);
            }
        }
        float v[4];
#pragma unroll
        for (int r = 0; r < 4; ++r) v[r] = fmaxf(acc[r] + ba[r], 0.f);
        if (RES) {
            int rr = 2 * i + 4;
            rr = (rr < res_valid - 1) ? rr : (res_valid - 1);
            int rsw = swz2(rr);
            int rcb = (mt * 32 + lg * 8) ^ rsw;
            ushortx4 rh = *(const ushortx4*)(lds + resH + rr * 128 + rcb);
            ushortx4 rl = *(const ushortx4*)(lds + resL + rr * 128 + rcb);
#pragma unroll
            for (int r = 0; r < 4; ++r)
                v[r] = fmaxf(v[r] + bf2f(rh[r]) + bf2f(rl[r]), 0.f);
        }
        if (FINAL) {
            if (i == 0) {
                float* scratch = (float*)(lds + SCRATCH_B);
#pragma unroll
                for (int r = 0; r < 4; ++r) scratch[co0 + r] = v[r];
            }
        } else {
            if (i < n_out) {
                ushortx4 h4, l4;
#pragma unroll
                for (int r = 0; r < 4; ++r) {
                    unsigned short hh = f2bf_rne(v[r]);
                    h4[r] = (short)hh;
                    l4[r] = (short)f2bf_rne(v[r] - bf2f(hh));
                }
                int wsw = swz2(i);
                int wcb = (mt * 32 + lg * 8) ^ wsw;
                *(ushortx4*)(lds + outH + i * 128 + wcb) = h4;
                *(ushortx4*)(lds + outL + i * 128 + wcb) = l4;
            }
        }
    }
}

__launch_bounds__(512, 4)
__global__ void encode_kernel(const float* __restrict__ sqs, const float* __restrict__ sks,
                              const float* __restrict__ sqt, const float* __restrict__ skt,
                              const unsigned short* __restrict__ wf,
                              const float* __restrict__ c1b, const float* __restrict__ c2b,
                              const float* __restrict__ pjw1, const float* __restrict__ pjb1,
                              const float* __restrict__ pjw2, const float* __restrict__ pjb2,
                              float* __restrict__ enc, float* __restrict__ proj) {
    __shared__ char lds[81920];
    int b = blockIdx.x;
    int s = blockIdx.y;
    const float* seq = (s == 0) ? sqs : (s == 1) ? sks : (s == 2) ? sqt : skt;
    const float4* base4 = reinterpret_cast<const float4*>(seq + ((size_t)b * L_SZ + WSTART) * C_SZ);
    int tid = threadIdx.x;

    // stage input: 125 rows x 64 ch -> bf16 hi/lo, [t][ci], swizzled
    for (int idx = tid; idx < 2000; idx += 512) {
        float4 v = base4[idx];
        int t = idx >> 4, c0 = (idx & 15) * 4;
        int cb = (c0 * 2) ^ swz2(t);
        float vv[4] = {v.x, v.y, v.z, v.w};
        ushortx4 h4, l4;
#pragma unroll
        for (int r = 0; r < 4; ++r) {
            unsigned short hh = f2bf_rne(vv[r]);
            h4[r] = (short)hh;
            l4[r] = (short)f2bf_rne(vv[r] - bf2f(hh));
        }
        *(ushortx4*)(lds + R0H + t * 128 + cb) = h4;
        *(ushortx4*)(lds + R0L + t * 128 + cb) = l4;
    }

    int w    = tid >> 6;
    int lane = tid & 63;
    int mt = w & 3, th = w >> 2;
    int lg = lane >> 4, li = lane & 15;
    const bf16x8* wf8 = (const bf16x8*)wf;

    bf16x8 A[3][2][2], An[3][2][2];
    loadA(A, wf8, 0, mt, lane);
    __syncthreads();

    const int n_in[5] = {125, 61, 29, 13, 5};
    const int n1a[5]  = {123, 59, 27, 11, 3};
    const int n2a[5]  = {61, 29, 13, 5, 1};
    const int t1a[5]  = {8, 4, 2, 1, 1};
    const int t2a[5]  = {4, 2, 1, 1, 1};

#pragma unroll
    for (int l = 0; l < 5; ++l) {
        int xH = (l & 1) ? R1H : R0H, xL = (l & 1) ? R1L : R0L;
        int yH = (l & 1) ? R0H : R1H, yL = (l & 1) ? R0L : R1L;
        loadA(An, wf8, l * 2 + 1, mt, lane);            // prefetch conv2 weights
        conv_pass<false, false>(lds, A, xH, xL, n_in[l], 1,
                                HHB, HLB, n1a[l], t1a[l], 0, 0, 0,
                                c1b + l * 64, mt, th, lg, li);
        __syncthreads();
        copyA(A, An);
        if (l < 4) loadA(An, wf8, l * 2 + 2, mt, lane); // prefetch next conv1 weights
        if (l < 4) {
            conv_pass<true, false>(lds, A, HHB, HLB, n1a[l], 2,
                                   yH, yL, n2a[l], t2a[l], xH, xL, n_in[l],
                                   c2b + l * 64, mt, th, lg, li);
        } else {
            conv_pass<true, true>(lds, A, HHB, HLB, n1a[l], 2,
                                  yH, yL, n2a[l], t2a[l], xH, xL, n_in[l],
                                  c2b + l * 64, mt, th, lg, li);
        }
        __syncthreads();
        copyA(A, An);
    }

    // ---- l2 normalize + write enc; keep normalized vector in LDS for fused proj ----
    float* xn = (float*)(lds + R0H);        // R0 dead after final pass
    if (tid < 64) {
        float vv = ((float*)(lds + SCRATCH_B))[tid];
        float sq = vv * vv;
#pragma unroll
        for (int off = 32; off; off >>= 1) sq += __shfl_xor(sq, off, 64);
        float norm = fmaxf(sqrtf(sq), 1e-12f);
        float nv = vv / norm;
        enc[((size_t)s * B_SZ + b) * 64 + tid] = nv;
        xn[tid] = nv;
    }
    __syncthreads();

    // ---- fused projection MLP + l2norm (only q_s / q_t blocks) ----
    if (s == 0 || s == 2) {
        float* hv = (float*)(lds + R1H);    // R1 dead after final pass
        if (tid < 256) {
            float acc = pjb1[tid];
            for (int c = 0; c < 64; ++c) acc = fmaf(xn[c], pjw1[c * 256 + tid], acc);
            hv[tid] = fmaxf(acc, 0.f);
        }
        __syncthreads();
        if (tid < 64) {
            float o = pjb2[tid];
            for (int j = 0; j < 256; ++j) o = fmaf(hv[j], pjw2[j * 64 + tid], o);
            float sq = o * o;
#pragma unroll
            for (int off = 32; off; off >>= 1) sq += __shfl_xor(sq, off, 64);
            float norm = fmaxf(sqrtf(sq), 1e-12f);
            int which = s >> 1;
            proj[((size_t)which * B_SZ + b) * 64 + tid] = o / norm;
        }
    }
}

// ---------------- logits: queue part (MFMA) + k^T part, one kernel ----------------
// grid (392, 2), 512 threads.
//   bx < 384 : 64-col queue stripe, all 256 rows (queue fetched exactly once)
//   bx >= 384: k^T part, row tile rt = bx-384 (32 rows x 256 cols, f32 VALU)
#define QLP 0        // P: [256][64] bf16 swizzled (32 KB)
#define QLQ 32768    // Q: [64 cols][64 k] bf16 swizzled (8 KB)
__launch_bounds__(512)
__global__ void qlogits_kernel(const float* __restrict__ proj, const float* __restrict__ enc,
                               const float* __restrict__ queue_s, const float* __restrict__ queue_t,
                               float* __restrict__ out) {
    __shared__ char lds[40960];
    int bx = blockIdx.x;
    int sz = blockIdx.y;
    int tid = threadIdx.x;
    long long outBase0 = (sz == 0) ? OFF_LOGITS_S : OFF_LOGITS_T;

    if (bx >= 384) {
        // ---- k^T part ----
        float (*pt)[65] = (float(*)[65])lds;
        int rt = bx - 384;
        const float* p = proj + ((size_t)sz * B_SZ + rt * 32) * 64;
        for (int idx = tid; idx < 32 * 64; idx += 512) {
            pt[idx >> 6][idx & 63] = p[idx];
        }
        __syncthreads();
        if (tid < 256) {
            float acc[32];
#pragma unroll
            for (int r = 0; r < 32; ++r) acc[r] = 0.f;
            int j = tid;
            const float* k = enc + ((size_t)(sz == 0 ? 1 : 3) * B_SZ + j) * 64;
            for (int c = 0; c < 64; ++c) {
                float bv = k[c];
#pragma unroll
                for (int r = 0; r < 32; ++r) acc[r] = fmaf(pt[r][c], bv, acc[r]);
            }
#pragma unroll
            for (int r = 0; r < 32; ++r) {
                out[outBase0 + (long long)(rt * 32 + r) * 24832 + j] = acc[r] * INV_T;
            }
        }
        return;
    }

    // ---- queue part ----
    int j0 = bx * 64;
    const float* p = proj + (size_t)sz * B_SZ * 64;
    const float* q = (sz == 0 ? queue_s : queue_t);

    {
        const float4* p4 = (const float4*)p;
#pragma unroll
        for (int pass = 0; pass < 8; ++pass) {
            int idx = pass * 512 + tid;
            float4 v = p4[idx];
            int row = idx >> 4, k0 = (idx & 15) * 4;
            ushortx4 h4;
            h4[0] = f2bf_rne(v.x); h4[1] = f2bf_rne(v.y);
            h4[2] = f2bf_rne(v.z); h4[3] = f2bf_rne(v.w);
            *(ushortx4*)(lds + QLP + row * 128 + ((k0 * 2) ^ ((row & 7) << 4))) = h4;
        }
    }
    {
#pragma unroll
        for (int pass = 0; pass < 2; ++pass) {
            int idx = pass * 512 + tid;
            int c = idx >> 4, jj0 = (idx & 15) * 4;
            float4 v = *(const float4*)(q + (size_t)c * KQ + j0 + jj0);
            float vv[4] = {v.x, v.y, v.z, v.w};
#pragma unroll
            for (int r = 0; r < 4; ++r) {
                int jj = jj0 + r;
                *(unsigned short*)(lds + QLQ + jj * 128 + ((c * 2) ^ ((jj & 7) << 4))) = f2bf_rne(vv[r]);
            }
        }
    }
    __syncthreads();

    int w = tid >> 6, lane = tid & 63;
    int r31 = lane & 31, hi = lane >> 5;
    int arow = w * 32 + r31;
    bf16x8 A[4];
#pragma unroll
    for (int ks = 0; ks < 4; ++ks)
        A[ks] = *(const bf16x8*)(lds + QLP + arow * 128 + (((ks * 16 + hi * 8) * 2) ^ ((arow & 7) << 4)));
    long long outBase = outBase0 + 256 + j0;
#pragma unroll
    for (int ct = 0; ct < 2; ++ct) {
        int col = ct * 32 + r31;
        bf16x8 Bf[4];
#pragma unroll
        for (int ks = 0; ks < 4; ++ks)
            Bf[ks] = *(const bf16x8*)(lds + QLQ + col * 128 + (((ks * 16 + hi * 8) * 2) ^ ((col & 7) << 4)));
        floatx16 acc;
#pragma unroll
        for (int r = 0; r < 16; ++r) acc[r] = 0.f;
#pragma unroll
        for (int ks = 0; ks < 4; ++ks)
            acc = __builtin_amdgcn_mfma_f32_32x32x16_bf16(A[ks], Bf[ks], acc, 0, 0, 0);
#pragma unroll
        for (int r = 0; r < 16; ++r) {
            int drow = (r & 3) + 8 * (r >> 2) + 4 * hi;
            out[outBase + (long long)(w * 32 + drow) * 24832 + ct * 32 + r31] = acc[r] * INV_T;
        }
    }
}

// ---------------- fused small heads: nn + domain + ys + fill ----------------
__global__ void heads_kernel(const float* __restrict__ enc, const float* __restrict__ stat,
                             const float* __restrict__ dw1, const float* __restrict__ db1,
                             const float* __restrict__ dw2, const float* __restrict__ db2,
                             const float* __restrict__ prw1, const float* __restrict__ prb1,
                             const float* __restrict__ prw2, const float* __restrict__ prb2,
                             float* __restrict__ out) {
    int bx = blockIdx.x;
    int tid = threadIdx.x;

    if (bx < 256) {
        // ---- nn argmin + logits_ts ----
        __shared__ float kt[64];
        __shared__ float qt[64];
        __shared__ float swv[4];
        __shared__ int   swj[4];
        int i = bx;
        if (tid < 64) {
            kt[tid] = enc[((size_t)3 * B_SZ + i) * 64 + tid];
            qt[tid] = enc[((size_t)2 * B_SZ + i) * 64 + tid];
        }
        __syncthreads();
        int j = tid;
        const float* qs = enc + (size_t)j * 64;
        float dkt = 0.f, dqt = 0.f, qq = 0.f, kk = 0.f;
        for (int c = 0; c < 64; ++c) {
            float v = qs[c];
            dkt = fmaf(kt[c], v, dkt);
            dqt = fmaf(qt[c], v, dqt);
            qq  = fmaf(v, v, qq);
            kk  = fmaf(kt[c], kt[c], kk);
        }
        out[OFF_LOGITS_TS + (long long)i * 256 + j] = dqt * INV_T;
        float d2 = kk + qq - 2.f * dkt;
        float bv = d2; int bj = j;
#pragma unroll
        for (int off = 32; off; off >>= 1) {
            float ov = __shfl_xor(bv, off, 64);
            int   oj = __shfl_xor(bj, off, 64);
            if (ov < bv || (ov == bv && oj < bj)) { bv = ov; bj = oj; }
        }
        int w = tid >> 6;
        if ((tid & 63) == 0) { swv[w] = bv; swj[w] = bj; }
        __syncthreads();
        if (tid == 0) {
            float best = swv[0]; int bi = swj[0];
#pragma unroll
            for (int k = 1; k < 4; ++k)
                if (swv[k] < best || (swv[k] == best && swj[k] < bi)) { best = swv[k]; bi = swj[k]; }
            out[OFF_LABELS_TS + i] = (float)bi;
        }
    } else if (bx < 768) {
        // ---- domain discriminator ----
        __shared__ float xv[64];
        __shared__ float red[256];
        int r = bx - 256;
        const float* x = enc + ((r < 256) ? ((size_t)0 * B_SZ + r) : ((size_t)2 * B_SZ + (r - 256))) * 64;
        if (tid < 64) xv[tid] = x[tid];
        __syncthreads();
        float h = db1[tid];
        for (int c = 0; c < 64; ++c) h = fmaf(xv[c], dw1[c * 256 + tid], h);
        h = fmaxf(h, 0.f);
        red[tid] = h * dw2[tid];
        __syncthreads();
        for (int s = 128; s; s >>= 1) {
            if (tid < s) red[tid] += red[tid + s];
            __syncthreads();
        }
        if (tid == 0) out[OFF_PRED_DOM + r] = red[0] + db2[0];
    } else if (bx < 1024) {
        // ---- y_s head ----
        __shared__ float xv[96];
        __shared__ float red[256];
        int b = bx - 768;
        if (tid < 64)       xv[tid] = enc[(size_t)b * 64 + tid];
        else if (tid < 96)  xv[tid] = stat[(size_t)b * 32 + (tid - 64)];
        __syncthreads();
        float h = prb1[tid];
        for (int c = 0; c < 96; ++c) h = fmaf(xv[c], prw1[c * 256 + tid], h);
        h = fmaxf(h, 0.f);
        for (int o = 0; o < 2; ++o) {
            red[tid] = h * prw2[tid * 2 + o];
            __syncthreads();
            for (int s = 128; s; s >>= 1) {
                if (tid < s) red[tid] += red[tid + s];
                __syncthreads();
            }
            if (tid == 0) out[OFF_YS + (long long)b * 2 + o] = red[0] + prb2[o];
            __syncthreads();
        }
    } else {
        // ---- labels fill ----
        int t = (bx - 1024) * 256 + tid;
        if (t < 256) {
            out[OFF_LABELS_S + t] = (float)t;
            out[OFF_LABELS_T + t] = (float)t;
        }
        if (t < 512) out[OFF_LABELS_DOM + t] = (t < 256) ? 1.f : 0.f;
    }
}

// ---------------- launch ----------------
extern "C" void kernel_launch(void* const* d_in, const int* in_sizes, int n_in,
                              void* d_out, int out_size, void* d_ws, size_t ws_size,
                              hipStream_t stream) {
    const float* sqs    = (const float*)d_in[0];
    const float* sks    = (const float*)d_in[1];
    const float* stat_s = (const float*)d_in[2];
    const float* sqt    = (const float*)d_in[3];
    const float* skt    = (const float*)d_in[4];
    const float* c1w    = (const float*)d_in[7];
    const float* c1b    = (const float*)d_in[8];
    const float* c2w    = (const float*)d_in[9];
    const float* c2b    = (const float*)d_in[10];
    const float* pjw1   = (const float*)d_in[11];
    const float* pjb1   = (const float*)d_in[12];
    const float* pjw2   = (const float*)d_in[13];
    const float* pjb2   = (const float*)d_in[14];
    const float* prw1   = (const float*)d_in[15];
    const float* prb1   = (const float*)d_in[16];
    const float* prw2   = (const float*)d_in[17];
    const float* prb2   = (const float*)d_in[18];
    const float* dw1    = (const float*)d_in[19];
    const float* db1    = (const float*)d_in[20];
    const float* dw2    = (const float*)d_in[21];
    const float* db2    = (const float*)d_in[22];
    const float* queue_s = (const float*)d_in[23];
    const float* queue_t = (const float*)d_in[24];

    float* out = (float*)d_out;
    unsigned short* wf = (unsigned short*)d_ws;               // 245760 halfs = 491520 B
    float* enc  = (float*)((char*)d_ws + 491520);             // 4*256*64 floats
    float* proj = enc + 65536;                                // 2*256*64 floats

    prep_frag_kernel<<<240, 512, 0, stream>>>(c1w, c2w, wf);
    encode_kernel<<<dim3(256, 4), 512, 0, stream>>>(sqs, sks, sqt, skt, wf, c1b, c2b,
                                                    pjw1, pjb1, pjw2, pjb2, enc, proj);
    qlogits_kernel<<<dim3(392, 2), 512, 0, stream>>>(proj, enc, queue_s, queue_t, out);
    heads_kernel<<<1026, 256, 0, stream>>>(enc, stat_s, dw1, db1, dw2, db2,
                                           prw1, prb1, prw2, prb2, out);
}

// Round 10
// 94.068 us; speedup vs baseline: 1.1766x; 1.1766x over previous
//
#include <hip/hip_runtime.h>
#include <hip/hip_bf16.h>

// ---------------- constants ----------------
#define B_SZ   256
#define L_SZ   1024
#define C_SZ   64
#define HID    256
#define KQ     24576
#define WIN    125          // receptive field of last position
#define WSTART (L_SZ - WIN) // 899

// output offsets (floats)
#define OFF_LOGITS_S   0LL
#define OFF_LABELS_S   6356992LL
#define OFF_LOGITS_T   6357248LL
#define OFF_LABELS_T   12714240LL
#define OFF_LOGITS_TS  12714496LL
#define OFF_LABELS_TS  12780032LL
#define OFF_PRED_DOM   12780288LL
#define OFF_LABELS_DOM 12780800LL
#define OFF_YS         12781312LL

#define INV_T (1.0f / 0.07f)

typedef __attribute__((ext_vector_type(8))) short  bf16x8;
typedef __attribute__((ext_vector_type(4))) float  floatx4;
typedef __attribute__((ext_vector_type(16))) float floatx16;
typedef __attribute__((ext_vector_type(4))) unsigned short ushortx4;

__device__ __forceinline__ unsigned short f2bf_rne(float x) {
    unsigned u = __float_as_uint(x);
    unsigned r = u + 0x7fffu + ((u >> 16) & 1u);
    return (unsigned short)(r >> 16);
}
__device__ __forceinline__ float bf2f(unsigned short h) {
    return __uint_as_float(((unsigned)h) << 16);
}

// stride-robust LDS swizzle: 2-way (free) for stride-1, conflict-free for stride-2
__device__ __forceinline__ int swz2(int r) { return ((r >> 1) & 7) << 4; }

// ---------------- weight A-fragment prep (16x16x32 layout) ----------------
__global__ void prep_frag_kernel(const float* __restrict__ c1w,
                                 const float* __restrict__ c2w,
                                 unsigned short* __restrict__ wf) {
    int bid = blockIdx.x;            // (st*3+tap)*8 + mt*2 + kb : 240 blocks
    int kb = bid & 1, mt = (bid >> 1) & 3;
    int sttap = bid >> 3;            // 0..29
    int tap = sttap % 3, st = sttap / 3;
    int l = st >> 1, cv = st & 1;
    int tid = threadIdx.x;           // 512
    int j = tid & 7, lane = tid >> 3;
    int co = mt * 16 + (lane & 15);
    int ci = kb * 32 + (lane >> 4) * 8 + j;
    const float* src = cv ? c2w : c1w;
    float w = src[((l * 64 + co) * 64 + ci) * 3 + tap];
    unsigned short hi = f2bf_rne(w);
    unsigned short lo = f2bf_rne(w - bf2f(hi));
    size_t b0 = ((((size_t)((st * 3 + tap) * 2 + 0)) * 4 + mt) * 2 + kb) * 512 + lane * 8 + j;
    size_t b1 = ((((size_t)((st * 3 + tap) * 2 + 1)) * 4 + mt) * 2 + kb) * 512 + lane * 8 + j;
    wf[b0] = hi;
    wf[b1] = lo;
}

// ---------------- TCN encode via MFMA (R6 structure) + fused proj ----------------
#define R0H 0
#define R0L 16384
#define R1H 32768
#define R1L 40960
#define HHB 49152
#define HLB 65536
#define SCRATCH_B 57344

template<bool RES, bool FINAL>
__device__ __forceinline__ void conv_pass(
    char* lds, const bf16x8* __restrict__ wf8,
    int st, int inH, int inL, int rows_valid, int stride,
    int outH, int outL, int n_out, int tiles,
    int resH, int resL, int res_valid,
    const float* __restrict__ bias,
    int mt, int th, int lg, int li, int lane)
{
    bf16x8 A[3][2][2];
#pragma unroll
    for (int tap = 0; tap < 3; ++tap)
#pragma unroll
        for (int h = 0; h < 2; ++h)
#pragma unroll
            for (int kb = 0; kb < 2; ++kb)
                A[tap][h][kb] = wf8[((((st * 3 + tap) * 2 + h) * 4 + mt) * 2 + kb) * 64 + lane];

    int co0 = mt * 16 + lg * 4;
    float4 b4 = *(const float4*)(bias + co0);
    float ba[4] = {b4.x, b4.y, b4.z, b4.w};

    for (int tt = th; tt < tiles; tt += 2) {
        int i = tt * 16 + li;
        floatx4 acc = {0.f, 0.f, 0.f, 0.f};
#pragma unroll
        for (int tap = 0; tap < 3; ++tap) {
            int jr = i * stride + tap;
            jr = (jr < rows_valid - 1) ? jr : (rows_valid - 1);
            int sw = swz2(jr);
            const char* pH = lds + inH + jr * 128;
            const char* pL = lds + inL + jr * 128;
#pragma unroll
            for (int kb = 0; kb < 2; ++kb) {
                int cb = (kb * 64 + lg * 16) ^ sw;
                bf16x8 bH = *(const bf16x8*)(pH + cb);
                bf16x8 bL = *(const bf16x8*)(pL + cb);
                acc = __builtin_amdgcn_mfma_f32_16x16x32_bf16(A[tap][0][kb], bH, acc, 0, 0, 0);
                acc = __builtin_amdgcn_mfma_f32_16x16x32_bf16(A[tap][0][kb], bL, acc, 0, 0, 0);
                acc = __builtin_amdgcn_mfma_f32_16x16x32_bf16(A[tap][1][kb], bH, acc, 0, 0, 0);
            }
        }
        float v[4];
#pragma unroll
        for (int r = 0; r < 4; ++r) v[r] = fmaxf(acc[r] + ba[r], 0.f);
        if (RES) {
            int rr = 2 * i + 4;
            rr = (rr < res_valid - 1) ? rr : (res_valid - 1);
            int rsw = swz2(rr);
            int rcb = (mt * 32 + lg * 8) ^ rsw;
            ushortx4 rh = *(const ushortx4*)(lds + resH + rr * 128 + rcb);
            ushortx4 rl = *(const ushortx4*)(lds + resL + rr * 128 + rcb);
#pragma unroll
            for (int r = 0; r < 4; ++r)
                v[r] = fmaxf(v[r] + bf2f(rh[r]) + bf2f(rl[r]), 0.f);
        }
        if (FINAL) {
            if (i == 0) {
                float* scratch = (float*)(lds + SCRATCH_B);
#pragma unroll
                for (int r = 0; r < 4; ++r) scratch[co0 + r] = v[r];
            }
        } else {
            if (i < n_out) {
                ushortx4 h4, l4;
#pragma unroll
                for (int r = 0; r < 4; ++r) {
                    unsigned short hh = f2bf_rne(v[r]);
                    h4[r] = (short)hh;
                    l4[r] = (short)f2bf_rne(v[r] - bf2f(hh));
                }
                int wsw = swz2(i);
                int wcb = (mt * 32 + lg * 8) ^ wsw;
                *(ushortx4*)(lds + outH + i * 128 + wcb) = h4;
                *(ushortx4*)(lds + outL + i * 128 + wcb) = l4;
            }
        }
    }
}

__launch_bounds__(512, 4)
__global__ void encode_kernel(const float* __restrict__ sqs, const float* __restrict__ sks,
                              const float* __restrict__ sqt, const float* __restrict__ skt,
                              const unsigned short* __restrict__ wf,
                              const float* __restrict__ c1b, const float* __restrict__ c2b,
                              const float* __restrict__ pjw1, const float* __restrict__ pjb1,
                              const float* __restrict__ pjw2, const float* __restrict__ pjb2,
                              float* __restrict__ enc, float* __restrict__ proj,
                              unsigned short* __restrict__ pbf) {
    __shared__ char lds[81920];
    int b = blockIdx.x;
    int s = blockIdx.y;
    const float* seq = (s == 0) ? sqs : (s == 1) ? sks : (s == 2) ? sqt : skt;
    const float4* base4 = reinterpret_cast<const float4*>(seq + ((size_t)b * L_SZ + WSTART) * C_SZ);
    int tid = threadIdx.x;

    // stage input: 125 rows x 64 ch -> bf16 hi/lo, [t][ci], swizzled
    for (int idx = tid; idx < 2000; idx += 512) {
        float4 v = base4[idx];
        int t = idx >> 4, c0 = (idx & 15) * 4;
        int cb = (c0 * 2) ^ swz2(t);
        float vv[4] = {v.x, v.y, v.z, v.w};
        ushortx4 h4, l4;
#pragma unroll
        for (int r = 0; r < 4; ++r) {
            unsigned short hh = f2bf_rne(vv[r]);
            h4[r] = (short)hh;
            l4[r] = (short)f2bf_rne(vv[r] - bf2f(hh));
        }
        *(ushortx4*)(lds + R0H + t * 128 + cb) = h4;
        *(ushortx4*)(lds + R0L + t * 128 + cb) = l4;
    }
    __syncthreads();

    int w    = tid >> 6;
    int lane = tid & 63;
    int mt = w & 3, th = w >> 2;
    int lg = lane >> 4, li = lane & 15;
    const bf16x8* wf8 = (const bf16x8*)wf;

    const int n_in[5] = {125, 61, 29, 13, 5};
    const int n1a[5]  = {123, 59, 27, 11, 3};
    const int n2a[5]  = {61, 29, 13, 5, 1};
    const int t1a[5]  = {8, 4, 2, 1, 1};
    const int t2a[5]  = {4, 2, 1, 1, 1};

#pragma unroll
    for (int l = 0; l < 5; ++l) {
        int xH = (l & 1) ? R1H : R0H, xL = (l & 1) ? R1L : R0L;
        int yH = (l & 1) ? R0H : R1H, yL = (l & 1) ? R0L : R1L;
        conv_pass<false, false>(lds, wf8, l * 2, xH, xL, n_in[l], 1,
                                HHB, HLB, n1a[l], t1a[l], 0, 0, 0,
                                c1b + l * 64, mt, th, lg, li, lane);
        __syncthreads();
        if (l < 4) {
            conv_pass<true, false>(lds, wf8, l * 2 + 1, HHB, HLB, n1a[l], 2,
                                   yH, yL, n2a[l], t2a[l], xH, xL, n_in[l],
                                   c2b + l * 64, mt, th, lg, li, lane);
        } else {
            conv_pass<true, true>(lds, wf8, l * 2 + 1, HHB, HLB, n1a[l], 2,
                                  yH, yL, n2a[l], t2a[l], xH, xL, n_in[l],
                                  c2b + l * 64, mt, th, lg, li, lane);
        }
        __syncthreads();
    }

    // ---- l2 normalize + write enc; keep normalized vector in LDS for fused proj ----
    float* xn = (float*)(lds + R0H);        // R0 dead after final pass
    if (tid < 64) {
        float vv = ((float*)(lds + SCRATCH_B))[tid];
        float sq = vv * vv;
#pragma unroll
        for (int off = 32; off; off >>= 1) sq += __shfl_xor(sq, off, 64);
        float norm = fmaxf(sqrtf(sq), 1e-12f);
        float nv = vv / norm;
        enc[((size_t)s * B_SZ + b) * 64 + tid] = nv;
        xn[tid] = nv;
    }
    __syncthreads();

    // ---- fused projection MLP + l2norm (only q_s / q_t blocks) ----
    if (s == 0 || s == 2) {
        float* hv = (float*)(lds + R1H);    // R1 dead after final pass
        if (tid < 256) {
            float acc = pjb1[tid];
            for (int c = 0; c < 64; ++c) acc = fmaf(xn[c], pjw1[c * 256 + tid], acc);
            hv[tid] = fmaxf(acc, 0.f);
        }
        __syncthreads();
        if (tid < 64) {
            float o = pjb2[tid];
            for (int j = 0; j < 256; ++j) o = fmaf(hv[j], pjw2[j * 64 + tid], o);
            float sq = o * o;
#pragma unroll
            for (int off = 32; off; off >>= 1) sq += __shfl_xor(sq, off, 64);
            float norm = fmaxf(sqrtf(sq), 1e-12f);
            float pv = o / norm;
            int which = s >> 1;
            proj[((size_t)which * B_SZ + b) * 64 + tid] = pv;
            pbf[((size_t)which * B_SZ + b) * 64 + tid] = f2bf_rne(pv);
        }
    }
}

// ---------------- logits: queue part (MFMA, A from global pbf) + k^T part ----------------
// grid (392, 2), 512 threads.
//   bx < 384 : 64-col queue stripe, all 256 rows (queue fetched exactly once)
//   bx >= 384: k^T part, row tile rt = bx-384 (32 rows x 256 cols, f32 VALU)
__launch_bounds__(512)
__global__ void qlogits_kernel(const float* __restrict__ proj,
                               const unsigned short* __restrict__ pbf,
                               const float* __restrict__ enc,
                               const float* __restrict__ queue_s, const float* __restrict__ queue_t,
                               float* __restrict__ out) {
    __shared__ char lds[8448];          // queue stripe (8192 B) or kT pt[32][65] (8320 B)
    int bx = blockIdx.x;
    int sz = blockIdx.y;
    int tid = threadIdx.x;
    long long outBase0 = (sz == 0) ? OFF_LOGITS_S : OFF_LOGITS_T;

    if (bx >= 384) {
        // ---- k^T part ----
        float (*pt)[65] = (float(*)[65])lds;
        int rt = bx - 384;
        const float* p = proj + ((size_t)sz * B_SZ + rt * 32) * 64;
        for (int idx = tid; idx < 32 * 64; idx += 512) {
            pt[idx >> 6][idx & 63] = p[idx];
        }
        __syncthreads();
        if (tid < 256) {
            float acc[32];
#pragma unroll
            for (int r = 0; r < 32; ++r) acc[r] = 0.f;
            int j = tid;
            const float* k = enc + ((size_t)(sz == 0 ? 1 : 3) * B_SZ + j) * 64;
            for (int c = 0; c < 64; ++c) {
                float bv = k[c];
#pragma unroll
                for (int r = 0; r < 32; ++r) acc[r] = fmaf(pt[r][c], bv, acc[r]);
            }
#pragma unroll
            for (int r = 0; r < 32; ++r) {
                out[outBase0 + (long long)(rt * 32 + r) * 24832 + j] = acc[r] * INV_T;
            }
        }
        return;
    }

    // ---- queue part ----
    int j0 = bx * 64;
    const float* q = (sz == 0 ? queue_s : queue_t);

    // stage queue stripe: 64 k-rows x 64 cols f32 -> bf16 transposed [col][k], swizzled
    {
#pragma unroll
        for (int pass = 0; pass < 2; ++pass) {
            int idx = pass * 512 + tid;          // 0..1023
            int c = idx >> 4, jj0 = (idx & 15) * 4;
            float4 v = *(const float4*)(q + (size_t)c * KQ + j0 + jj0);
            float vv[4] = {v.x, v.y, v.z, v.w};
#pragma unroll
            for (int r = 0; r < 4; ++r) {
                int jj = jj0 + r;
                *(unsigned short*)(lds + jj * 128 + ((c * 2) ^ ((jj & 7) << 4))) = f2bf_rne(vv[r]);
            }
        }
    }
    __syncthreads();

    int w = tid >> 6, lane = tid & 63;
    int r31 = lane & 31, hi = lane >> 5;
    int arow = w * 32 + r31;
    // A-fragments straight from global (L2-resident bf16 proj): k = ks*16 + hi*8 + j
    const bf16x8* pa = (const bf16x8*)(pbf + ((size_t)sz * B_SZ + arow) * 64);
    bf16x8 A[4];
#pragma unroll
    for (int ks = 0; ks < 4; ++ks)
        A[ks] = pa[ks * 2 + hi];
    long long outBase = outBase0 + 256 + j0;
#pragma unroll
    for (int ct = 0; ct < 2; ++ct) {
        int col = ct * 32 + r31;
        bf16x8 Bf[4];
#pragma unroll
        for (int ks = 0; ks < 4; ++ks)
            Bf[ks] = *(const bf16x8*)(lds + col * 128 + (((ks * 16 + hi * 8) * 2) ^ ((col & 7) << 4)));
        floatx16 acc;
#pragma unroll
        for (int r = 0; r < 16; ++r) acc[r] = 0.f;
#pragma unroll
        for (int ks = 0; ks < 4; ++ks)
            acc = __builtin_amdgcn_mfma_f32_32x32x16_bf16(A[ks], Bf[ks], acc, 0, 0, 0);
#pragma unroll
        for (int r = 0; r < 16; ++r) {
            int drow = (r & 3) + 8 * (r >> 2) + 4 * hi;
            out[outBase + (long long)(w * 32 + drow) * 24832 + ct * 32 + r31] = acc[r] * INV_T;
        }
    }
}

// ---------------- fused small heads: nn + domain + ys + fill ----------------
__global__ void heads_kernel(const float* __restrict__ enc, const float* __restrict__ stat,
                             const float* __restrict__ dw1, const float* __restrict__ db1,
                             const float* __restrict__ dw2, const float* __restrict__ db2,
                             const float* __restrict__ prw1, const float* __restrict__ prb1,
                             const float* __restrict__ prw2, const float* __restrict__ prb2,
                             float* __restrict__ out) {
    int bx = blockIdx.x;
    int tid = threadIdx.x;

    if (bx < 256) {
        // ---- nn argmin + logits_ts ----
        __shared__ float kt[64];
        __shared__ float qt[64];
        __shared__ float swv[4];
        __shared__ int   swj[4];
        int i = bx;
        if (tid < 64) {
            kt[tid] = enc[((size_t)3 * B_SZ + i) * 64 + tid];
            qt[tid] = enc[((size_t)2 * B_SZ + i) * 64 + tid];
        }
        __syncthreads();
        int j = tid;
        const float* qs = enc + (size_t)j * 64;
        float dkt = 0.f, dqt = 0.f, qq = 0.f, kk = 0.f;
        for (int c = 0; c < 64; ++c) {
            float v = qs[c];
            dkt = fmaf(kt[c], v, dkt);
            dqt = fmaf(qt[c], v, dqt);
            qq  = fmaf(v, v, qq);
            kk  = fmaf(kt[c], kt[c], kk);
        }
        out[OFF_LOGITS_TS + (long long)i * 256 + j] = dqt * INV_T;
        float d2 = kk + qq - 2.f * dkt;
        float bv = d2; int bj = j;
#pragma unroll
        for (int off = 32; off; off >>= 1) {
            float ov = __shfl_xor(bv, off, 64);
            int   oj = __shfl_xor(bj, off, 64);
            if (ov < bv || (ov == bv && oj < bj)) { bv = ov; bj = oj; }
        }
        int w = tid >> 6;
        if ((tid & 63) == 0) { swv[w] = bv; swj[w] = bj; }
        __syncthreads();
        if (tid == 0) {
            float best = swv[0]; int bi = swj[0];
#pragma unroll
            for (int k = 1; k < 4; ++k)
                if (swv[k] < best || (swv[k] == best && swj[k] < bi)) { best = swv[k]; bi = swj[k]; }
            out[OFF_LABELS_TS + i] = (float)bi;
        }
    } else if (bx < 768) {
        // ---- domain discriminator ----
        __shared__ float xv[64];
        __shared__ float red[256];
        int r = bx - 256;
        const float* x = enc + ((r < 256) ? ((size_t)0 * B_SZ + r) : ((size_t)2 * B_SZ + (r - 256))) * 64;
        if (tid < 64) xv[tid] = x[tid];
        __syncthreads();
        float h = db1[tid];
        for (int c = 0; c < 64; ++c) h = fmaf(xv[c], dw1[c * 256 + tid], h);
        h = fmaxf(h, 0.f);
        red[tid] = h * dw2[tid];
        __syncthreads();
        for (int s = 128; s; s >>= 1) {
            if (tid < s) red[tid] += red[tid + s];
            __syncthreads();
        }
        if (tid == 0) out[OFF_PRED_DOM + r] = red[0] + db2[0];
    } else if (bx < 1024) {
        // ---- y_s head ----
        __shared__ float xv[96];
        __shared__ float red[256];
        int b = bx - 768;
        if (tid < 64)       xv[tid] = enc[(size_t)b * 64 + tid];
        else if (tid < 96)  xv[tid] = stat[(size_t)b * 32 + (tid - 64)];
        __syncthreads();
        float h = prb1[tid];
        for (int c = 0; c < 96; ++c) h = fmaf(xv[c], prw1[c * 256 + tid], h);
        h = fmaxf(h, 0.f);
        for (int o = 0; o < 2; ++o) {
            red[tid] = h * prw2[tid * 2 + o];
            __syncthreads();
            for (int s = 128; s; s >>= 1) {
                if (tid < s) red[tid] += red[tid + s];
                __syncthreads();
            }
            if (tid == 0) out[OFF_YS + (long long)b * 2 + o] = red[0] + prb2[o];
            __syncthreads();
        }
    } else {
        // ---- labels fill ----
        int t = (bx - 1024) * 256 + tid;
        if (t < 256) {
            out[OFF_LABELS_S + t] = (float)t;
            out[OFF_LABELS_T + t] = (float)t;
        }
        if (t < 512) out[OFF_LABELS_DOM + t] = (t < 256) ? 1.f : 0.f;
    }
}

// ---------------- launch ----------------
extern "C" void kernel_launch(void* const* d_in, const int* in_sizes, int n_in,
                              void* d_out, int out_size, void* d_ws, size_t ws_size,
                              hipStream_t stream) {
    const float* sqs    = (const float*)d_in[0];
    const float* sks    = (const float*)d_in[1];
    const float* stat_s = (const float*)d_in[2];
    const float* sqt    = (const float*)d_in[3];
    const float* skt    = (const float*)d_in[4];
    const float* c1w    = (const float*)d_in[7];
    const float* c1b    = (const float*)d_in[8];
    const float* c2w    = (const float*)d_in[9];
    const float* c2b    = (const float*)d_in[10];
    const float* pjw1   = (const float*)d_in[11];
    const float* pjb1   = (const float*)d_in[12];
    const float* pjw2   = (const float*)d_in[13];
    const float* pjb2   = (const float*)d_in[14];
    const float* prw1   = (const float*)d_in[15];
    const float* prb1   = (const float*)d_in[16];
    const float* prw2   = (const float*)d_in[17];
    const float* prb2   = (const float*)d_in[18];
    const float* dw1    = (const float*)d_in[19];
    const float* db1    = (const float*)d_in[20];
    const float* dw2    = (const float*)d_in[21];
    const float* db2    = (const float*)d_in[22];
    const float* queue_s = (const float*)d_in[23];
    const float* queue_t = (const float*)d_in[24];

    float* out = (float*)d_out;
    unsigned short* wf = (unsigned short*)d_ws;               // 245760 halfs = 491520 B
    float* enc  = (float*)((char*)d_ws + 491520);             // 4*256*64 floats (262144 B)
    float* proj = enc + 65536;                                // 2*256*64 floats (131072 B)
    unsigned short* pbf = (unsigned short*)(proj + 32768);    // 2*256*64 bf16 (65536 B)

    prep_frag_kernel<<<240, 512, 0, stream>>>(c1w, c2w, wf);
    encode_kernel<<<dim3(256, 4), 512, 0, stream>>>(sqs, sks, sqt, skt, wf, c1b, c2b,
                                                    pjw1, pjb1, pjw2, pjb2, enc, proj, pbf);
    qlogits_kernel<<<dim3(392, 2), 512, 0, stream>>>(proj, pbf, enc, queue_s, queue_t, out);
    heads_kernel<<<1026, 256, 0, stream>>>(enc, stat_s, dw1, db1, dw2, db2,
                                           prw1, prb1, prw2, prb2, out);
}

// Round 11
// 92.622 us; speedup vs baseline: 1.1950x; 1.0156x over previous
//
#include <hip/hip_runtime.h>
#include <hip/hip_bf16.h>

// ---------------- constants ----------------
#define B_SZ   256
#define L_SZ   1024
#define C_SZ   64
#define HID    256
#define KQ     24576
#define WIN    125          // receptive field of last position
#define WSTART (L_SZ - WIN) // 899

// output offsets (floats)
#define OFF_LOGITS_S   0LL
#define OFF_LABELS_S   6356992LL
#define OFF_LOGITS_T   6357248LL
#define OFF_LABELS_T   12714240LL
#define OFF_LOGITS_TS  12714496LL
#define OFF_LABELS_TS  12780032LL
#define OFF_PRED_DOM   12780288LL
#define OFF_LABELS_DOM 12780800LL
#define OFF_YS         12781312LL

#define INV_T (1.0f / 0.07f)

typedef __attribute__((ext_vector_type(8))) short  bf16x8;
typedef __attribute__((ext_vector_type(4))) float  floatx4;
typedef __attribute__((ext_vector_type(16))) float floatx16;
typedef __attribute__((ext_vector_type(4))) unsigned short ushortx4;

__device__ __forceinline__ unsigned short f2bf_rne(float x) {
    unsigned u = __float_as_uint(x);
    unsigned r = u + 0x7fffu + ((u >> 16) & 1u);
    return (unsigned short)(r >> 16);
}
__device__ __forceinline__ float bf2f(unsigned short h) {
    return __uint_as_float(((unsigned)h) << 16);
}

// stride-robust LDS swizzle: 2-way (free) for stride-1, conflict-free for stride-2
__device__ __forceinline__ int swz2(int r) { return ((r >> 1) & 7) << 4; }

// ---------------- weight A-fragment prep (16x16x32 layout) ----------------
__global__ void prep_frag_kernel(const float* __restrict__ c1w,
                                 const float* __restrict__ c2w,
                                 unsigned short* __restrict__ wf) {
    int bid = blockIdx.x;            // (st*3+tap)*8 + mt*2 + kb : 240 blocks
    int kb = bid & 1, mt = (bid >> 1) & 3;
    int sttap = bid >> 3;            // 0..29
    int tap = sttap % 3, st = sttap / 3;
    int l = st >> 1, cv = st & 1;
    int tid = threadIdx.x;           // 512
    int j = tid & 7, lane = tid >> 3;
    int co = mt * 16 + (lane & 15);
    int ci = kb * 32 + (lane >> 4) * 8 + j;
    const float* src = cv ? c2w : c1w;
    float w = src[((l * 64 + co) * 64 + ci) * 3 + tap];
    unsigned short hi = f2bf_rne(w);
    unsigned short lo = f2bf_rne(w - bf2f(hi));
    size_t b0 = ((((size_t)((st * 3 + tap) * 2 + 0)) * 4 + mt) * 2 + kb) * 512 + lane * 8 + j;
    size_t b1 = ((((size_t)((st * 3 + tap) * 2 + 1)) * 4 + mt) * 2 + kb) * 512 + lane * 8 + j;
    wf[b0] = hi;
    wf[b1] = lo;
}

// ---------------- TCN encode via MFMA (R6 structure) + fused proj ----------------
#define R0H 0
#define R0L 16384
#define R1H 32768
#define R1L 40960
#define HHB 49152
#define HLB 65536
#define SCRATCH_B 57344

template<bool RES, bool FINAL>
__device__ __forceinline__ void conv_pass(
    char* lds, const bf16x8* __restrict__ wf8,
    int st, int inH, int inL, int rows_valid, int stride,
    int outH, int outL, int n_out, int tiles,
    int resH, int resL, int res_valid,
    const float* __restrict__ bias,
    int mt, int th, int lg, int li, int lane)
{
    if (th >= tiles) return;         // no tiles for this wave: skip A loads entirely

    bf16x8 A[3][2][2];
#pragma unroll
    for (int tap = 0; tap < 3; ++tap)
#pragma unroll
        for (int h = 0; h < 2; ++h)
#pragma unroll
            for (int kb = 0; kb < 2; ++kb)
                A[tap][h][kb] = wf8[((((st * 3 + tap) * 2 + h) * 4 + mt) * 2 + kb) * 64 + lane];

    int co0 = mt * 16 + lg * 4;
    float4 b4 = *(const float4*)(bias + co0);
    float ba[4] = {b4.x, b4.y, b4.z, b4.w};

    for (int tt = th; tt < tiles; tt += 2) {
        int i = tt * 16 + li;
        floatx4 acc = {0.f, 0.f, 0.f, 0.f};
#pragma unroll
        for (int tap = 0; tap < 3; ++tap) {
            int jr = i * stride + tap;
            jr = (jr < rows_valid - 1) ? jr : (rows_valid - 1);
            int sw = swz2(jr);
            const char* pH = lds + inH + jr * 128;
            const char* pL = lds + inL + jr * 128;
#pragma unroll
            for (int kb = 0; kb < 2; ++kb) {
                int cb = (kb * 64 + lg * 16) ^ sw;
                bf16x8 bH = *(const bf16x8*)(pH + cb);
                bf16x8 bL = *(const bf16x8*)(pL + cb);
                acc = __builtin_amdgcn_mfma_f32_16x16x32_bf16(A[tap][0][kb], bH, acc, 0, 0, 0);
                acc = __builtin_amdgcn_mfma_f32_16x16x32_bf16(A[tap][0][kb], bL, acc, 0, 0, 0);
                acc = __builtin_amdgcn_mfma_f32_16x16x32_bf16(A[tap][1][kb], bH, acc, 0, 0, 0);
            }
        }
        float v[4];
#pragma unroll
        for (int r = 0; r < 4; ++r) v[r] = fmaxf(acc[r] + ba[r], 0.f);
        if (RES) {
            int rr = 2 * i + 4;
            rr = (rr < res_valid - 1) ? rr : (res_valid - 1);
            int rsw = swz2(rr);
            int rcb = (mt * 32 + lg * 8) ^ rsw;
            ushortx4 rh = *(const ushortx4*)(lds + resH + rr * 128 + rcb);
            ushortx4 rl = *(const ushortx4*)(lds + resL + rr * 128 + rcb);
#pragma unroll
            for (int r = 0; r < 4; ++r)
                v[r] = fmaxf(v[r] + bf2f(rh[r]) + bf2f(rl[r]), 0.f);
        }
        if (FINAL) {
            if (i == 0) {
                float* scratch = (float*)(lds + SCRATCH_B);
#pragma unroll
                for (int r = 0; r < 4; ++r) scratch[co0 + r] = v[r];
            }
        } else {
            if (i < n_out) {
                ushortx4 h4, l4;
#pragma unroll
                for (int r = 0; r < 4; ++r) {
                    unsigned short hh = f2bf_rne(v[r]);
                    h4[r] = (short)hh;
                    l4[r] = (short)f2bf_rne(v[r] - bf2f(hh));
                }
                int wsw = swz2(i);
                int wcb = (mt * 32 + lg * 8) ^ wsw;
                *(ushortx4*)(lds + outH + i * 128 + wcb) = h4;
                *(ushortx4*)(lds + outL + i * 128 + wcb) = l4;
            }
        }
    }
}

__launch_bounds__(512, 4)
__global__ void encode_kernel(const float* __restrict__ sqs, const float* __restrict__ sks,
                              const float* __restrict__ sqt, const float* __restrict__ skt,
                              const unsigned short* __restrict__ wf,
                              const float* __restrict__ c1b, const float* __restrict__ c2b,
                              const float* __restrict__ pjw1, const float* __restrict__ pjb1,
                              const float* __restrict__ pjw2, const float* __restrict__ pjb2,
                              float* __restrict__ enc, float* __restrict__ proj,
                              unsigned short* __restrict__ pbf) {
    __shared__ char lds[81920];
    int b = blockIdx.x;
    int s = blockIdx.y;
    const float* seq = (s == 0) ? sqs : (s == 1) ? sks : (s == 2) ? sqt : skt;
    const float4* base4 = reinterpret_cast<const float4*>(seq + ((size_t)b * L_SZ + WSTART) * C_SZ);
    int tid = threadIdx.x;

    // stage input: 125 rows x 64 ch -> bf16 hi/lo, [t][ci], swizzled
    for (int idx = tid; idx < 2000; idx += 512) {
        float4 v = base4[idx];
        int t = idx >> 4, c0 = (idx & 15) * 4;
        int cb = (c0 * 2) ^ swz2(t);
        float vv[4] = {v.x, v.y, v.z, v.w};
        ushortx4 h4, l4;
#pragma unroll
        for (int r = 0; r < 4; ++r) {
            unsigned short hh = f2bf_rne(vv[r]);
            h4[r] = (short)hh;
            l4[r] = (short)f2bf_rne(vv[r] - bf2f(hh));
        }
        *(ushortx4*)(lds + R0H + t * 128 + cb) = h4;
        *(ushortx4*)(lds + R0L + t * 128 + cb) = l4;
    }
    __syncthreads();

    int w    = tid >> 6;
    int lane = tid & 63;
    int mt = w & 3, th = w >> 2;
    int lg = lane >> 4, li = lane & 15;
    const bf16x8* wf8 = (const bf16x8*)wf;

    const int n_in[5] = {125, 61, 29, 13, 5};
    const int n1a[5]  = {123, 59, 27, 11, 3};
    const int n2a[5]  = {61, 29, 13, 5, 1};
    const int t1a[5]  = {8, 4, 2, 1, 1};
    const int t2a[5]  = {4, 2, 1, 1, 1};

#pragma unroll
    for (int l = 0; l < 5; ++l) {
        int xH = (l & 1) ? R1H : R0H, xL = (l & 1) ? R1L : R0L;
        int yH = (l & 1) ? R0H : R1H, yL = (l & 1) ? R0L : R1L;
        conv_pass<false, false>(lds, wf8, l * 2, xH, xL, n_in[l], 1,
                                HHB, HLB, n1a[l], t1a[l], 0, 0, 0,
                                c1b + l * 64, mt, th, lg, li, lane);
        __syncthreads();
        if (l < 4) {
            conv_pass<true, false>(lds, wf8, l * 2 + 1, HHB, HLB, n1a[l], 2,
                                   yH, yL, n2a[l], t2a[l], xH, xL, n_in[l],
                                   c2b + l * 64, mt, th, lg, li, lane);
        } else {
            conv_pass<true, true>(lds, wf8, l * 2 + 1, HHB, HLB, n1a[l], 2,
                                  yH, yL, n2a[l], t2a[l], xH, xL, n_in[l],
                                  c2b + l * 64, mt, th, lg, li, lane);
        }
        __syncthreads();
    }

    // ---- l2 normalize + write enc; keep normalized vector in LDS for fused proj ----
    float* xn = (float*)(lds + R0H);        // R0 dead after final pass
    if (tid < 64) {
        float vv = ((float*)(lds + SCRATCH_B))[tid];
        float sq = vv * vv;
#pragma unroll
        for (int off = 32; off; off >>= 1) sq += __shfl_xor(sq, off, 64);
        float norm = fmaxf(sqrtf(sq), 1e-12f);
        float nv = vv / norm;
        enc[((size_t)s * B_SZ + b) * 64 + tid] = nv;
        xn[tid] = nv;
    }
    __syncthreads();

    // ---- fused projection MLP + l2norm (only q_s / q_t blocks), fully parallel ----
    if (s == 0 || s == 2) {
        float* hv   = (float*)(lds + R1H);          // 256 floats
        float* red2 = (float*)(lds + R1H + 1024);   // 2 x 256 floats
        float* red8 = (float*)(lds + R1H + 3072);   // 8 x 64 floats
        // layer 1: o2 = tid&255, part = tid>>8 (2 parts x 32 c), coalesced pjw1 cols
        {
            int o2 = tid & 255, part = tid >> 8;
            float acc = 0.f;
            const float* wcol = pjw1 + o2;
            int c0 = part * 32;
            for (int c = c0; c < c0 + 32; ++c) acc = fmaf(xn[c], wcol[c * 256], acc);
            red2[part * 256 + o2] = acc;
        }
        __syncthreads();
        if (tid < 256) hv[tid] = fmaxf(red2[tid] + red2[256 + tid] + pjb1[tid], 0.f);
        __syncthreads();
        // layer 2: wave wv covers j in [wv*32, wv*32+32), o = lane; coalesced pjw2 cols
        {
            int wv = tid >> 6, o = tid & 63;
            float acc = 0.f;
            const float* wcol = pjw2 + o;
            int j0 = wv * 32;
            for (int j = j0; j < j0 + 32; ++j) acc = fmaf(hv[j], wcol[j * 64], acc);
            red8[wv * 64 + o] = acc;
        }
        __syncthreads();
        if (tid < 64) {
            float o = pjb2[tid];
#pragma unroll
            for (int k = 0; k < 8; ++k) o += red8[k * 64 + tid];
            float sq = o * o;
#pragma unroll
            for (int off = 32; off; off >>= 1) sq += __shfl_xor(sq, off, 64);
            float norm = fmaxf(sqrtf(sq), 1e-12f);
            float pv = o / norm;
            int which = s >> 1;
            proj[((size_t)which * B_SZ + b) * 64 + tid] = pv;
            pbf[((size_t)which * B_SZ + b) * 64 + tid] = f2bf_rne(pv);
        }
    }
}

// ---------------- logits: queue part (MFMA, A from global pbf) + k^T part ----------------
// grid (392, 2), 512 threads.
__launch_bounds__(512)
__global__ void qlogits_kernel(const float* __restrict__ proj,
                               const unsigned short* __restrict__ pbf,
                               const float* __restrict__ enc,
                               const float* __restrict__ queue_s, const float* __restrict__ queue_t,
                               float* __restrict__ out) {
    __shared__ char lds[8448];          // queue stripe (8192 B) or kT pt[32][65] (8320 B)
    int bx = blockIdx.x;
    int sz = blockIdx.y;
    int tid = threadIdx.x;
    long long outBase0 = (sz == 0) ? OFF_LOGITS_S : OFF_LOGITS_T;

    if (bx >= 384) {
        // ---- k^T part ----
        float (*pt)[65] = (float(*)[65])lds;
        int rt = bx - 384;
        const float* p = proj + ((size_t)sz * B_SZ + rt * 32) * 64;
        for (int idx = tid; idx < 32 * 64; idx += 512) {
            pt[idx >> 6][idx & 63] = p[idx];
        }
        __syncthreads();
        if (tid < 256) {
            float acc[32];
#pragma unroll
            for (int r = 0; r < 32; ++r) acc[r] = 0.f;
            int j = tid;
            const float* k = enc + ((size_t)(sz == 0 ? 1 : 3) * B_SZ + j) * 64;
            for (int c = 0; c < 64; ++c) {
                float bv = k[c];
#pragma unroll
                for (int r = 0; r < 32; ++r) acc[r] = fmaf(pt[r][c], bv, acc[r]);
            }
#pragma unroll
            for (int r = 0; r < 32; ++r) {
                out[outBase0 + (long long)(rt * 32 + r) * 24832 + j] = acc[r] * INV_T;
            }
        }
        return;
    }

    // ---- queue part ----
    int j0 = bx * 64;
    const float* q = (sz == 0 ? queue_s : queue_t);

    {
#pragma unroll
        for (int pass = 0; pass < 2; ++pass) {
            int idx = pass * 512 + tid;          // 0..1023
            int c = idx >> 4, jj0 = (idx & 15) * 4;
            float4 v = *(const float4*)(q + (size_t)c * KQ + j0 + jj0);
            float vv[4] = {v.x, v.y, v.z, v.w};
#pragma unroll
            for (int r = 0; r < 4; ++r) {
                int jj = jj0 + r;
                *(unsigned short*)(lds + jj * 128 + ((c * 2) ^ ((jj & 7) << 4))) = f2bf_rne(vv[r]);
            }
        }
    }
    __syncthreads();

    int w = tid >> 6, lane = tid & 63;
    int r31 = lane & 31, hi = lane >> 5;
    int arow = w * 32 + r31;
    const bf16x8* pa = (const bf16x8*)(pbf + ((size_t)sz * B_SZ + arow) * 64);
    bf16x8 A[4];
#pragma unroll
    for (int ks = 0; ks < 4; ++ks)
        A[ks] = pa[ks * 2 + hi];
    long long outBase = outBase0 + 256 + j0;
#pragma unroll
    for (int ct = 0; ct < 2; ++ct) {
        int col = ct * 32 + r31;
        bf16x8 Bf[4];
#pragma unroll
        for (int ks = 0; ks < 4; ++ks)
            Bf[ks] = *(const bf16x8*)(lds + col * 128 + (((ks * 16 + hi * 8) * 2) ^ ((col & 7) << 4)));
        floatx16 acc;
#pragma unroll
        for (int r = 0; r < 16; ++r) acc[r] = 0.f;
#pragma unroll
        for (int ks = 0; ks < 4; ++ks)
            acc = __builtin_amdgcn_mfma_f32_32x32x16_bf16(A[ks], Bf[ks], acc, 0, 0, 0);
#pragma unroll
        for (int r = 0; r < 16; ++r) {
            int drow = (r & 3) + 8 * (r >> 2) + 4 * hi;
            out[outBase + (long long)(w * 32 + drow) * 24832 + ct * 32 + r31] = acc[r] * INV_T;
        }
    }
}

// ---------------- fused small heads: nn + domain + ys + fill ----------------
__global__ void heads_kernel(const float* __restrict__ enc, const float* __restrict__ stat,
                             const float* __restrict__ dw1, const float* __restrict__ db1,
                             const float* __restrict__ dw2, const float* __restrict__ db2,
                             const float* __restrict__ prw1, const float* __restrict__ prb1,
                             const float* __restrict__ prw2, const float* __restrict__ prb2,
                             float* __restrict__ out) {
    int bx = blockIdx.x;
    int tid = threadIdx.x;

    if (bx < 256) {
        // ---- nn argmin + logits_ts ----
        __shared__ float kt[64];
        __shared__ float qt[64];
        __shared__ float swv[4];
        __shared__ int   swj[4];
        int i = bx;
        if (tid < 64) {
            kt[tid] = enc[((size_t)3 * B_SZ + i) * 64 + tid];
            qt[tid] = enc[((size_t)2 * B_SZ + i) * 64 + tid];
        }
        __syncthreads();
        int j = tid;
        const float* qs = enc + (size_t)j * 64;
        float dkt = 0.f, dqt = 0.f, qq = 0.f, kk = 0.f;
        for (int c = 0; c < 64; ++c) {
            float v = qs[c];
            dkt = fmaf(kt[c], v, dkt);
            dqt = fmaf(qt[c], v, dqt);
            qq  = fmaf(v, v, qq);
            kk  = fmaf(kt[c], kt[c], kk);
        }
        out[OFF_LOGITS_TS + (long long)i * 256 + j] = dqt * INV_T;
        float d2 = kk + qq - 2.f * dkt;
        float bv = d2; int bj = j;
#pragma unroll
        for (int off = 32; off; off >>= 1) {
            float ov = __shfl_xor(bv, off, 64);
            int   oj = __shfl_xor(bj, off, 64);
            if (ov < bv || (ov == bv && oj < bj)) { bv = ov; bj = oj; }
        }
        int w = tid >> 6;
        if ((tid & 63) == 0) { swv[w] = bv; swj[w] = bj; }
        __syncthreads();
        if (tid == 0) {
            float best = swv[0]; int bi = swj[0];
#pragma unroll
            for (int k = 1; k < 4; ++k)
                if (swv[k] < best || (swv[k] == best && swj[k] < bi)) { best = swv[k]; bi = swj[k]; }
            out[OFF_LABELS_TS + i] = (float)bi;
        }
    } else if (bx < 768) {
        // ---- domain discriminator ----
        __shared__ float xv[64];
        __shared__ float red[256];
        int r = bx - 256;
        const float* x = enc + ((r < 256) ? ((size_t)0 * B_SZ + r) : ((size_t)2 * B_SZ + (r - 256))) * 64;
        if (tid < 64) xv[tid] = x[tid];
        __syncthreads();
        float h = db1[tid];
        for (int c = 0; c < 64; ++c) h = fmaf(xv[c], dw1[c * 256 + tid], h);
        h = fmaxf(h, 0.f);
        red[tid] = h * dw2[tid];
        __syncthreads();
        for (int s = 128; s; s >>= 1) {
            if (tid < s) red[tid] += red[tid + s];
            __syncthreads();
        }
        if (tid == 0) out[OFF_PRED_DOM + r] = red[0] + db2[0];
    } else if (bx < 1024) {
        // ---- y_s head ----
        __shared__ float xv[96];
        __shared__ float red[256];
        int b = bx - 768;
        if (tid < 64)       xv[tid] = enc[(size_t)b * 64 + tid];
        else if (tid < 96)  xv[tid] = stat[(size_t)b * 32 + (tid - 64)];
        __syncthreads();
        float h = prb1[tid];
        for (int c = 0; c < 96; ++c) h = fmaf(xv[c], prw1[c * 256 + tid], h);
        h = fmaxf(h, 0.f);
        for (int o = 0; o < 2; ++o) {
            red[tid] = h * prw2[tid * 2 + o];
            __syncthreads();
            for (int s = 128; s; s >>= 1) {
                if (tid < s) red[tid] += red[tid + s];
                __syncthreads();
            }
            if (tid == 0) out[OFF_YS + (long long)b * 2 + o] = red[0] + prb2[o];
            __syncthreads();
        }
    } else {
        // ---- labels fill ----
        int t = (bx - 1024) * 256 + tid;
        if (t < 256) {
            out[OFF_LABELS_S + t] = (float)t;
            out[OFF_LABELS_T + t] = (float)t;
        }
        if (t < 512) out[OFF_LABELS_DOM + t] = (t < 256) ? 1.f : 0.f;
    }
}

// ---------------- launch ----------------
extern "C" void kernel_launch(void* const* d_in, const int* in_sizes, int n_in,
                              void* d_out, int out_size, void* d_ws, size_t ws_size,
                              hipStream_t stream) {
    const float* sqs    = (const float*)d_in[0];
    const float* sks    = (const float*)d_in[1];
    const float* stat_s = (const float*)d_in[2];
    const float* sqt    = (const float*)d_in[3];
    const float* skt    = (const float*)d_in[4];
    const float* c1w    = (const float*)d_in[7];
    const float* c1b    = (const float*)d_in[8];
    const float* c2w    = (const float*)d_in[9];
    const float* c2b    = (const float*)d_in[10];
    const float* pjw1   = (const float*)d_in[11];
    const float* pjb1   = (const float*)d_in[12];
    const float* pjw2   = (const float*)d_in[13];
    const float* pjb2   = (const float*)d_in[14];
    const float* prw1   = (const float*)d_in[15];
    const float* prb1   = (const float*)d_in[16];
    const float* prw2   = (const float*)d_in[17];
    const float* prb2   = (const float*)d_in[18];
    const float* dw1    = (const float*)d_in[19];
    const float* db1    = (const float*)d_in[20];
    const float* dw2    = (const float*)d_in[21];
    const float* db2    = (const float*)d_in[22];
    const float* queue_s = (const float*)d_in[23];
    const float* queue_t = (const float*)d_in[24];

    float* out = (float*)d_out;
    unsigned short* wf = (unsigned short*)d_ws;               // 245760 halfs = 491520 B
    float* enc  = (float*)((char*)d_ws + 491520);             // 4*256*64 floats (262144 B)
    float* proj = enc + 65536;                                // 2*256*64 floats (131072 B)
    unsigned short* pbf = (unsigned short*)(proj + 32768);    // 2*256*64 bf16 (65536 B)

    prep_frag_kernel<<<240, 512, 0, stream>>>(c1w, c2w, wf);
    encode_kernel<<<dim3(256, 4), 512, 0, stream>>>(sqs, sks, sqt, skt, wf, c1b, c2b,
                                                    pjw1, pjb1, pjw2, pjb2, enc, proj, pbf);
    qlogits_kernel<<<dim3(392, 2), 512, 0, stream>>>(proj, pbf, enc, queue_s, queue_t, out);
    heads_kernel<<<1026, 256, 0, stream>>>(enc, stat_s, dw1, db1, dw2, db2,
                                           prw1, prb1, prw2, prb2, out);
}

// Round 12
// 89.228 us; speedup vs baseline: 1.2405x; 1.0380x over previous
//
#include <hip/hip_runtime.h>
#include <hip/hip_bf16.h>

// ---------------- constants ----------------
#define B_SZ   256
#define L_SZ   1024
#define C_SZ   64
#define HID    256
#define KQ     24576
#define WIN    125          // receptive field of last position
#define WSTART (L_SZ - WIN) // 899

// output offsets (floats)
#define OFF_LOGITS_S   0LL
#define OFF_LABELS_S   6356992LL
#define OFF_LOGITS_T   6357248LL
#define OFF_LABELS_T   12714240LL
#define OFF_LOGITS_TS  12714496LL
#define OFF_LABELS_TS  12780032LL
#define OFF_PRED_DOM   12780288LL
#define OFF_LABELS_DOM 12780800LL
#define OFF_YS         12781312LL

#define INV_T (1.0f / 0.07f)

typedef __attribute__((ext_vector_type(8))) short  bf16x8;
typedef __attribute__((ext_vector_type(4))) float  floatx4;
typedef __attribute__((ext_vector_type(16))) float floatx16;
typedef __attribute__((ext_vector_type(4))) unsigned short ushortx4;

__device__ __forceinline__ unsigned short f2bf_rne(float x) {
    unsigned u = __float_as_uint(x);
    unsigned r = u + 0x7fffu + ((u >> 16) & 1u);
    return (unsigned short)(r >> 16);
}
__device__ __forceinline__ float bf2f(unsigned short h) {
    return __uint_as_float(((unsigned)h) << 16);
}

// stride-robust LDS swizzle: 2-way (free) for stride-1, conflict-free for stride-2
__device__ __forceinline__ int swz2(int r) { return ((r >> 1) & 7) << 4; }

// ---------------- weight A-fragment prep (16x16x32 layout) ----------------
__global__ void prep_frag_kernel(const float* __restrict__ c1w,
                                 const float* __restrict__ c2w,
                                 unsigned short* __restrict__ wf) {
    int bid = blockIdx.x;            // (st*3+tap)*8 + mt*2 + kb : 240 blocks
    int kb = bid & 1, mt = (bid >> 1) & 3;
    int sttap = bid >> 3;            // 0..29
    int tap = sttap % 3, st = sttap / 3;
    int l = st >> 1, cv = st & 1;
    int tid = threadIdx.x;           // 512
    int j = tid & 7, lane = tid >> 3;
    int co = mt * 16 + (lane & 15);
    int ci = kb * 32 + (lane >> 4) * 8 + j;
    const float* src = cv ? c2w : c1w;
    float w = src[((l * 64 + co) * 64 + ci) * 3 + tap];
    unsigned short hi = f2bf_rne(w);
    unsigned short lo = f2bf_rne(w - bf2f(hi));
    size_t b0 = ((((size_t)((st * 3 + tap) * 2 + 0)) * 4 + mt) * 2 + kb) * 512 + lane * 8 + j;
    size_t b1 = ((((size_t)((st * 3 + tap) * 2 + 1)) * 4 + mt) * 2 + kb) * 512 + lane * 8 + j;
    wf[b0] = hi;
    wf[b1] = lo;
}

// ---------------- TCN encode via MFMA: 4 waves (wave = co tile), unique A loads ----------------
#define R0H 0
#define R0L 16384
#define R1H 32768
#define R1L 40960
#define HHB 49152
#define HLB 65536
#define SCRATCH_B 57344

template<bool RES, bool FINAL>
__device__ __forceinline__ void conv_pass(
    char* lds, const bf16x8* __restrict__ wf8,
    int st, int inH, int inL, int rows_valid, int stride,
    int outH, int outL, int n_out, int tiles,
    int resH, int resL, int res_valid,
    const float* __restrict__ bias,
    int mt, int lg, int li, int lane)
{
    bf16x8 A[3][2][2];
#pragma unroll
    for (int tap = 0; tap < 3; ++tap)
#pragma unroll
        for (int h = 0; h < 2; ++h)
#pragma unroll
            for (int kb = 0; kb < 2; ++kb)
                A[tap][h][kb] = wf8[((((st * 3 + tap) * 2 + h) * 4 + mt) * 2 + kb) * 64 + lane];

    int co0 = mt * 16 + lg * 4;
    float4 b4 = *(const float4*)(bias + co0);
    float ba[4] = {b4.x, b4.y, b4.z, b4.w};

    for (int tt = 0; tt < tiles; ++tt) {
        int i = tt * 16 + li;
        floatx4 acc = {0.f, 0.f, 0.f, 0.f};
#pragma unroll
        for (int tap = 0; tap < 3; ++tap) {
            int jr = i * stride + tap;
            jr = (jr < rows_valid - 1) ? jr : (rows_valid - 1);
            int sw = swz2(jr);
            const char* pH = lds + inH + jr * 128;
            const char* pL = lds + inL + jr * 128;
#pragma unroll
            for (int kb = 0; kb < 2; ++kb) {
                int cb = (kb * 64 + lg * 16) ^ sw;
                bf16x8 bH = *(const bf16x8*)(pH + cb);
                bf16x8 bL = *(const bf16x8*)(pL + cb);
                acc = __builtin_amdgcn_mfma_f32_16x16x32_bf16(A[tap][0][kb], bH, acc, 0, 0, 0);
                acc = __builtin_amdgcn_mfma_f32_16x16x32_bf16(A[tap][0][kb], bL, acc, 0, 0, 0);
                acc = __builtin_amdgcn_mfma_f32_16x16x32_bf16(A[tap][1][kb], bH, acc, 0, 0, 0);
            }
        }
        float v[4];
#pragma unroll
        for (int r = 0; r < 4; ++r) v[r] = fmaxf(acc[r] + ba[r], 0.f);
        if (RES) {
            int rr = 2 * i + 4;
            rr = (rr < res_valid - 1) ? rr : (res_valid - 1);
            int rsw = swz2(rr);
            int rcb = (mt * 32 + lg * 8) ^ rsw;
            ushortx4 rh = *(const ushortx4*)(lds + resH + rr * 128 + rcb);
            ushortx4 rl = *(const ushortx4*)(lds + resL + rr * 128 + rcb);
#pragma unroll
            for (int r = 0; r < 4; ++r)
                v[r] = fmaxf(v[r] + bf2f(rh[r]) + bf2f(rl[r]), 0.f);
        }
        if (FINAL) {
            if (i == 0) {
                float* scratch = (float*)(lds + SCRATCH_B);
#pragma unroll
                for (int r = 0; r < 4; ++r) scratch[co0 + r] = v[r];
            }
        } else {
            if (i < n_out) {
                ushortx4 h4, l4;
#pragma unroll
                for (int r = 0; r < 4; ++r) {
                    unsigned short hh = f2bf_rne(v[r]);
                    h4[r] = (short)hh;
                    l4[r] = (short)f2bf_rne(v[r] - bf2f(hh));
                }
                int wsw = swz2(i);
                int wcb = (mt * 32 + lg * 8) ^ wsw;
                *(ushortx4*)(lds + outH + i * 128 + wcb) = h4;
                *(ushortx4*)(lds + outL + i * 128 + wcb) = l4;
            }
        }
    }
}

__launch_bounds__(256)
__global__ void encode_kernel(const float* __restrict__ sqs, const float* __restrict__ sks,
                              const float* __restrict__ sqt, const float* __restrict__ skt,
                              const unsigned short* __restrict__ wf,
                              const float* __restrict__ c1b, const float* __restrict__ c2b,
                              const float* __restrict__ pjw1, const float* __restrict__ pjb1,
                              const float* __restrict__ pjw2, const float* __restrict__ pjb2,
                              float* __restrict__ enc, float* __restrict__ proj,
                              unsigned short* __restrict__ pbf) {
    __shared__ char lds[81920];
    int b = blockIdx.x;
    int s = blockIdx.y;
    const float* seq = (s == 0) ? sqs : (s == 1) ? sks : (s == 2) ? sqt : skt;
    const float4* base4 = reinterpret_cast<const float4*>(seq + ((size_t)b * L_SZ + WSTART) * C_SZ);
    int tid = threadIdx.x;

    // stage input: 125 rows x 64 ch -> bf16 hi/lo, [t][ci], swizzled
    for (int idx = tid; idx < 2000; idx += 256) {
        float4 v = base4[idx];
        int t = idx >> 4, c0 = (idx & 15) * 4;
        int cb = (c0 * 2) ^ swz2(t);
        float vv[4] = {v.x, v.y, v.z, v.w};
        ushortx4 h4, l4;
#pragma unroll
        for (int r = 0; r < 4; ++r) {
            unsigned short hh = f2bf_rne(vv[r]);
            h4[r] = (short)hh;
            l4[r] = (short)f2bf_rne(vv[r] - bf2f(hh));
        }
        *(ushortx4*)(lds + R0H + t * 128 + cb) = h4;
        *(ushortx4*)(lds + R0L + t * 128 + cb) = l4;
    }
    __syncthreads();

    int mt   = tid >> 6;          // wave = co tile, does ALL tiles of every pass
    int lane = tid & 63;
    int lg = lane >> 4, li = lane & 15;
    const bf16x8* wf8 = (const bf16x8*)wf;

    const int n_in[5] = {125, 61, 29, 13, 5};
    const int n1a[5]  = {123, 59, 27, 11, 3};
    const int n2a[5]  = {61, 29, 13, 5, 1};
    const int t1a[5]  = {8, 4, 2, 1, 1};
    const int t2a[5]  = {4, 2, 1, 1, 1};

#pragma unroll
    for (int l = 0; l < 5; ++l) {
        int xH = (l & 1) ? R1H : R0H, xL = (l & 1) ? R1L : R0L;
        int yH = (l & 1) ? R0H : R1H, yL = (l & 1) ? R0L : R1L;
        conv_pass<false, false>(lds, wf8, l * 2, xH, xL, n_in[l], 1,
                                HHB, HLB, n1a[l], t1a[l], 0, 0, 0,
                                c1b + l * 64, mt, lg, li, lane);
        __syncthreads();
        if (l < 4) {
            conv_pass<true, false>(lds, wf8, l * 2 + 1, HHB, HLB, n1a[l], 2,
                                   yH, yL, n2a[l], t2a[l], xH, xL, n_in[l],
                                   c2b + l * 64, mt, lg, li, lane);
        } else {
            conv_pass<true, true>(lds, wf8, l * 2 + 1, HHB, HLB, n1a[l], 2,
                                  yH, yL, n2a[l], t2a[l], xH, xL, n_in[l],
                                  c2b + l * 64, mt, lg, li, lane);
        }
        __syncthreads();
    }

    // ---- l2 normalize + write enc; keep normalized vector in LDS for fused proj ----
    float* xn = (float*)(lds + R0H);        // R0 dead after final pass
    if (tid < 64) {
        float vv = ((float*)(lds + SCRATCH_B))[tid];
        float sq = vv * vv;
#pragma unroll
        for (int off = 32; off; off >>= 1) sq += __shfl_xor(sq, off, 64);
        float norm = fmaxf(sqrtf(sq), 1e-12f);
        float nv = vv / norm;
        enc[((size_t)s * B_SZ + b) * 64 + tid] = nv;
        xn[tid] = nv;
    }
    __syncthreads();

    // ---- fused projection MLP + l2norm (only q_s / q_t blocks), 256 threads ----
    if (s == 0 || s == 2) {
        float* hv   = (float*)(lds + R1H);          // 256 floats
        float* red4 = (float*)(lds + R1H + 1024);   // 4 x 64 floats
        // layer 1: thread tid computes hv[tid] (coalesced pjw1 columns)
        {
            float acc = pjb1[tid];
            const float* wcol = pjw1 + tid;
            for (int c = 0; c < 64; ++c) acc = fmaf(xn[c], wcol[c * 256], acc);
            hv[tid] = fmaxf(acc, 0.f);
        }
        __syncthreads();
        // layer 2: wave wv covers j in [wv*64, wv*64+64), o = lane (coalesced pjw2 cols)
        {
            int wv = tid >> 6, o = tid & 63;
            float acc = 0.f;
            const float* wcol = pjw2 + o;
            int j0 = wv * 64;
            for (int j = j0; j < j0 + 64; ++j) acc = fmaf(hv[j], wcol[j * 64], acc);
            red4[wv * 64 + o] = acc;
        }
        __syncthreads();
        if (tid < 64) {
            float o = pjb2[tid];
#pragma unroll
            for (int k = 0; k < 4; ++k) o += red4[k * 64 + tid];
            float sq = o * o;
#pragma unroll
            for (int off = 32; off; off >>= 1) sq += __shfl_xor(sq, off, 64);
            float norm = fmaxf(sqrtf(sq), 1e-12f);
            float pv = o / norm;
            int which = s >> 1;
            proj[((size_t)which * B_SZ + b) * 64 + tid] = pv;
            pbf[((size_t)which * B_SZ + b) * 64 + tid] = f2bf_rne(pv);
        }
    }
}

// ---------------- logits: queue part (MFMA, A from global pbf) + k^T part ----------------
// grid (392, 2), 512 threads.
__launch_bounds__(512)
__global__ void qlogits_kernel(const float* __restrict__ proj,
                               const unsigned short* __restrict__ pbf,
                               const float* __restrict__ enc,
                               const float* __restrict__ queue_s, const float* __restrict__ queue_t,
                               float* __restrict__ out) {
    __shared__ char lds[8448];          // queue stripe (8192 B) or kT pt[32][65] (8320 B)
    int bx = blockIdx.x;
    int sz = blockIdx.y;
    int tid = threadIdx.x;
    long long outBase0 = (sz == 0) ? OFF_LOGITS_S : OFF_LOGITS_T;

    if (bx >= 384) {
        // ---- k^T part ----
        float (*pt)[65] = (float(*)[65])lds;
        int rt = bx - 384;
        const float* p = proj + ((size_t)sz * B_SZ + rt * 32) * 64;
        for (int idx = tid; idx < 32 * 64; idx += 512) {
            pt[idx >> 6][idx & 63] = p[idx];
        }
        __syncthreads();
        if (tid < 256) {
            float acc[32];
#pragma unroll
            for (int r = 0; r < 32; ++r) acc[r] = 0.f;
            int j = tid;
            const float* k = enc + ((size_t)(sz == 0 ? 1 : 3) * B_SZ + j) * 64;
            for (int c = 0; c < 64; ++c) {
                float bv = k[c];
#pragma unroll
                for (int r = 0; r < 32; ++r) acc[r] = fmaf(pt[r][c], bv, acc[r]);
            }
#pragma unroll
            for (int r = 0; r < 32; ++r) {
                out[outBase0 + (long long)(rt * 32 + r) * 24832 + j] = acc[r] * INV_T;
            }
        }
        return;
    }

    // ---- queue part ----
    int j0 = bx * 64;
    const float* q = (sz == 0 ? queue_s : queue_t);

    {
#pragma unroll
        for (int pass = 0; pass < 2; ++pass) {
            int idx = pass * 512 + tid;          // 0..1023
            int c = idx >> 4, jj0 = (idx & 15) * 4;
            float4 v = *(const float4*)(q + (size_t)c * KQ + j0 + jj0);
            float vv[4] = {v.x, v.y, v.z, v.w};
#pragma unroll
            for (int r = 0; r < 4; ++r) {
                int jj = jj0 + r;
                *(unsigned short*)(lds + jj * 128 + ((c * 2) ^ ((jj & 7) << 4))) = f2bf_rne(vv[r]);
            }
        }
    }
    __syncthreads();

    int w = tid >> 6, lane = tid & 63;
    int r31 = lane & 31, hi = lane >> 5;
    int arow = w * 32 + r31;
    const bf16x8* pa = (const bf16x8*)(pbf + ((size_t)sz * B_SZ + arow) * 64);
    bf16x8 A[4];
#pragma unroll
    for (int ks = 0; ks < 4; ++ks)
        A[ks] = pa[ks * 2 + hi];
    long long outBase = outBase0 + 256 + j0;
#pragma unroll
    for (int ct = 0; ct < 2; ++ct) {
        int col = ct * 32 + r31;
        bf16x8 Bf[4];
#pragma unroll
        for (int ks = 0; ks < 4; ++ks)
            Bf[ks] = *(const bf16x8*)(lds + col * 128 + (((ks * 16 + hi * 8) * 2) ^ ((col & 7) << 4)));
        floatx16 acc;
#pragma unroll
        for (int r = 0; r < 16; ++r) acc[r] = 0.f;
#pragma unroll
        for (int ks = 0; ks < 4; ++ks)
            acc = __builtin_amdgcn_mfma_f32_32x32x16_bf16(A[ks], Bf[ks], acc, 0, 0, 0);
#pragma unroll
        for (int r = 0; r < 16; ++r) {
            int drow = (r & 3) + 8 * (r >> 2) + 4 * hi;
            out[outBase + (long long)(w * 32 + drow) * 24832 + ct * 32 + r31] = acc[r] * INV_T;
        }
    }
}

// ---------------- fused small heads: nn + domain + ys + fill ----------------
__global__ void heads_kernel(const float* __restrict__ enc, const float* __restrict__ stat,
                             const float* __restrict__ dw1, const float* __restrict__ db1,
                             const float* __restrict__ dw2, const float* __restrict__ db2,
                             const float* __restrict__ prw1, const float* __restrict__ prb1,
                             const float* __restrict__ prw2, const float* __restrict__ prb2,
                             float* __restrict__ out) {
    int bx = blockIdx.x;
    int tid = threadIdx.x;

    if (bx < 256) {
        // ---- nn argmin + logits_ts ----
        __shared__ float kt[64];
        __shared__ float qt[64];
        __shared__ float swv[4];
        __shared__ int   swj[4];
        int i = bx;
        if (tid < 64) {
            kt[tid] = enc[((size_t)3 * B_SZ + i) * 64 + tid];
            qt[tid] = enc[((size_t)2 * B_SZ + i) * 64 + tid];
        }
        __syncthreads();
        int j = tid;
        const float* qs = enc + (size_t)j * 64;
        float dkt = 0.f, dqt = 0.f, qq = 0.f, kk = 0.f;
        for (int c = 0; c < 64; ++c) {
            float v = qs[c];
            dkt = fmaf(kt[c], v, dkt);
            dqt = fmaf(qt[c], v, dqt);
            qq  = fmaf(v, v, qq);
            kk  = fmaf(kt[c], kt[c], kk);
        }
        out[OFF_LOGITS_TS + (long long)i * 256 + j] = dqt * INV_T;
        float d2 = kk + qq - 2.f * dkt;
        float bv = d2; int bj = j;
#pragma unroll
        for (int off = 32; off; off >>= 1) {
            float ov = __shfl_xor(bv, off, 64);
            int   oj = __shfl_xor(bj, off, 64);
            if (ov < bv || (ov == bv && oj < bj)) { bv = ov; bj = oj; }
        }
        int w = tid >> 6;
        if ((tid & 63) == 0) { swv[w] = bv; swj[w] = bj; }
        __syncthreads();
        if (tid == 0) {
            float best = swv[0]; int bi = swj[0];
#pragma unroll
            for (int k = 1; k < 4; ++k)
                if (swv[k] < best || (swv[k] == best && swj[k] < bi)) { best = swv[k]; bi = swj[k]; }
            out[OFF_LABELS_TS + i] = (float)bi;
        }
    } else if (bx < 768) {
        // ---- domain discriminator ----
        __shared__ float xv[64];
        __shared__ float red[256];
        int r = bx - 256;
        const float* x = enc + ((r < 256) ? ((size_t)0 * B_SZ + r) : ((size_t)2 * B_SZ + (r - 256))) * 64;
        if (tid < 64) xv[tid] = x[tid];
        __syncthreads();
        float h = db1[tid];
        for (int c = 0; c < 64; ++c) h = fmaf(xv[c], dw1[c * 256 + tid], h);
        h = fmaxf(h, 0.f);
        red[tid] = h * dw2[tid];
        __syncthreads();
        for (int s = 128; s; s >>= 1) {
            if (tid < s) red[tid] += red[tid + s];
            __syncthreads();
        }
        if (tid == 0) out[OFF_PRED_DOM + r] = red[0] + db2[0];
    } else if (bx < 1024) {
        // ---- y_s head ----
        __shared__ float xv[96];
        __shared__ float red[256];
        int b = bx - 768;
        if (tid < 64)       xv[tid] = enc[(size_t)b * 64 + tid];
        else if (tid < 96)  xv[tid] = stat[(size_t)b * 32 + (tid - 64)];
        __syncthreads();
        float h = prb1[tid];
        for (int c = 0; c < 96; ++c) h = fmaf(xv[c], prw1[c * 256 + tid], h);
        h = fmaxf(h, 0.f);
        for (int o = 0; o < 2; ++o) {
            red[tid] = h * prw2[tid * 2 + o];
            __syncthreads();
            for (int s = 128; s; s >>= 1) {
                if (tid < s) red[tid] += red[tid + s];
                __syncthreads();
            }
            if (tid == 0) out[OFF_YS + (long long)b * 2 + o] = red[0] + prb2[o];
            __syncthreads();
        }
    } else {
        // ---- labels fill ----
        int t = (bx - 1024) * 256 + tid;
        if (t < 256) {
            out[OFF_LABELS_S + t] = (float)t;
            out[OFF_LABELS_T + t] = (float)t;
        }
        if (t < 512) out[OFF_LABELS_DOM + t] = (t < 256) ? 1.f : 0.f;
    }
}

// ---------------- launch ----------------
extern "C" void kernel_launch(void* const* d_in, const int* in_sizes, int n_in,
                              void* d_out, int out_size, void* d_ws, size_t ws_size,
                              hipStream_t stream) {
    const float* sqs    = (const float*)d_in[0];
    const float* sks    = (const float*)d_in[1];
    const float* stat_s = (const float*)d_in[2];
    const float* sqt    = (const float*)d_in[3];
    const float* skt    = (const float*)d_in[4];
    const float* c1w    = (const float*)d_in[7];
    const float* c1b    = (const float*)d_in[8];
    const float* c2w    = (const float*)d_in[9];
    const float* c2b    = (const float*)d_in[10];
    const float* pjw1   = (const float*)d_in[11];
    const float* pjb1   = (const float*)d_in[12];
    const float* pjw2   = (const float*)d_in[13];
    const float* pjb2   = (const float*)d_in[14];
    const float* prw1   = (const float*)d_in[15];
    const float* prb1   = (const float*)d_in[16];
    const float* prw2   = (const float*)d_in[17];
    const float* prb2   = (const float*)d_in[18];
    const float* dw1    = (const float*)d_in[19];
    const float* db1    = (const float*)d_in[20];
    const float* dw2    = (const float*)d_in[21];
    const float* db2    = (const float*)d_in[22];
    const float* queue_s = (const float*)d_in[23];
    const float* queue_t = (const float*)d_in[24];

    float* out = (float*)d_out;
    unsigned short* wf = (unsigned short*)d_ws;               // 245760 halfs = 491520 B
    float* enc  = (float*)((char*)d_ws + 491520);             // 4*256*64 floats (262144 B)
    float* proj = enc + 65536;                                // 2*256*64 floats (131072 B)
    unsigned short* pbf = (unsigned short*)(proj + 32768);    // 2*256*64 bf16 (65536 B)

    prep_frag_kernel<<<240, 512, 0, stream>>>(c1w, c2w, wf);
    encode_kernel<<<dim3(256, 4), 256, 0, stream>>>(sqs, sks, sqt, skt, wf, c1b, c2b,
                                                    pjw1, pjb1, pjw2, pjb2, enc, proj, pbf);
    qlogits_kernel<<<dim3(392, 2), 512, 0, stream>>>(proj, pbf, enc, queue_s, queue_t, out);
    heads_kernel<<<1026, 256, 0, stream>>>(enc, stat_s, dw1, db1, dw2, db2,
                                           prw1, prb1, prw2, prb2, out);
}